// Round 5
// baseline (407.653 us; speedup 1.0000x reference)
//
#include <hip/hip_runtime.h>
#include <hip/hip_bf16.h>

#define NN 100000
#define NE 1600000
#define NPART 8
#define PSZ 12500   // NN / NPART
#define NCHUNK 128  // fill: chunks per partition; grid = NPART*NCHUNK = 1024

typedef unsigned short u16;
typedef unsigned int u32;
using frag  = __attribute__((ext_vector_type(8))) short;   // 8 bf16 = 4 VGPR
using f32x4 = __attribute__((ext_vector_type(4))) float;   // MFMA C/D

// ---------------- workspace layout (byte offsets) ----------------
// cnt 400KB | offsets 400KB | cursor 400KB | ptail/psum/flag | csr 6.4MB
// Wst1/Wst2 64KB | xb 25.6MB | aggb 25.6MB  -> ~60.6MB total (known-good size)
#define OFF_CNT   (0)
#define OFF_OFFS  (512u << 10)
#define OFF_CUR   (1u << 20)
#define OFF_TAIL  (1536u << 10)
#define OFF_CSR   (2u << 20)
#define OFF_WT1   (8704u << 10)
#define OFF_WT2   ((8704u << 10) + 65536u)
#define OFF_XB    (9u << 20)
#define OFF_AGGB  (35037184u)   // OFF_XB + 25,600,000

// round-to-nearest-even f32 -> bf16 bits
__device__ __forceinline__ u16 f2bf(float f) {
    u32 u = __float_as_uint(f);
    u32 r = u + 0x7fffu + ((u >> 16) & 1u);
    return (u16)(r >> 16);
}

__global__ void detect_kernel(const void* edges, int* flag) {
    if (threadIdx.x == 0 && blockIdx.x == 0) {
        const long long* e = (const long long*)edges;
        int ok = 1;
        for (int i = 0; i < 4; i++) {
            long long v = e[i];
            if (v < 0 || v >= NN) ok = 0;
        }
        *flag = ok;
    }
}

// single pass over dst (12.8MB read once); atomics are fabric-level regardless
__global__ __launch_bounds__(256) void count_kernel(const void* edges, const int* flag,
                                                    int* cnt) {
    int i = blockIdx.x * 256 + threadIdx.x;
    if (i >= NE) return;
    int f = *flag;
    int d = f ? (int)((const long long*)edges)[NE + i]
              : ((const int*)edges)[NE + i];
    atomicAdd(&cnt[d], 1);
}

// per-partition edge totals: block p reduces cnt[p*PSZ .. p*PSZ+PSZ)
__global__ void psum_kernel(const int* cnt, int* psum) {
    __shared__ int red[4];
    int p = blockIdx.x;
    int t = threadIdx.x;
    int s = 0;
    for (int i = t; i < PSZ; i += 256) s += cnt[p * PSZ + i];
    for (int off = 32; off > 0; off >>= 1) s += __shfl_down(s, off, 64);
    if ((t & 63) == 0) red[t >> 6] = s;
    __syncthreads();
    if (t == 0) psum[p] = red[0] + red[1] + red[2] + red[3];
}

__global__ void pbase_kernel(const int* psum, int* ptail) {
    if (threadIdx.x == 0 && blockIdx.x == 0) {
        int acc = 0;
        for (int p = 0; p < NPART; p++) { ptail[p] = acc; acc += psum[p]; }
    }
}

// offsets[n] = alloc within partition n/PSZ's CONTIGUOUS csr region.
// Wave-aggregated: shfl inclusive scan + 1 atomic per wave (lane 63).
__global__ __launch_bounds__(256) void alloc_part_kernel(const int* cnt, int* offsets,
                                                         int* ptail) {
    int n = blockIdx.x * 256 + threadIdx.x;
    int lane = threadIdx.x & 63;
    int c = (n < NN) ? cnt[n] : 0;
    int nfirst = blockIdx.x * 256 + (threadIdx.x & ~63);
    int nlast = nfirst + 63;
    if (nlast >= NN) nlast = NN - 1;
    int sc = c;  // inclusive scan over the wave
#pragma unroll
    for (int off = 1; off < 64; off <<= 1) {
        int v = __shfl_up(sc, off, 64);
        if (lane >= off) sc += v;
    }
    int excl = sc - c;
    if (nfirst / PSZ == nlast / PSZ) {   // wave entirely inside one partition
        int base = 0;
        if (lane == 63) base = atomicAdd(&ptail[nfirst / PSZ], sc);
        base = __shfl(base, 63, 64);
        if (n < NN) offsets[n] = base + excl;
    } else {                             // rare boundary wave (7 of 1563)
        if (n < NN) offsets[n] = atomicAdd(&ptail[n / PSZ], c);
    }
}

// 8-way dst-partitioned fill; partition p's csr region is now CONTIGUOUS
// (~800KB) -> stays resident in the owning XCD's L2, each line written once.
__global__ __launch_bounds__(256) void fill_part_kernel(const void* edges, const int* flag,
                                                        const int* offsets, int* cursor,
                                                        int* csr) {
    int part = blockIdx.x & (NPART - 1);
    int chunk = blockIdx.x >> 3;
    int lo = part * PSZ;
    int f = *flag;
    if (f) {
        const long long* e = (const long long*)edges;
        for (int i = chunk * 256 + threadIdx.x; i < NE; i += 256 * NCHUNK) {
            int d = (int)e[NE + i];
            if ((u32)(d - lo) < (u32)PSZ) {
                int s = (int)e[i];
                int pos = atomicAdd(&cursor[d], 1);
                csr[offsets[d] + pos] = s;
            }
        }
    } else {
        const int* e = (const int*)edges;
        for (int i = chunk * 256 + threadIdx.x; i < NE; i += 256 * NCHUNK) {
            int d = e[NE + i];
            if ((u32)(d - lo) < (u32)PSZ) {
                int s = e[i];
                int pos = atomicAdd(&cursor[d], 1);
                csr[offsets[d] + pos] = s;
            }
        }
    }
}

// Wst[kb*1024 + col*8 + i] = bf16( k<128 ? Wl[col][k] : Wr[col][k-128] ), k = kb*8+i
__global__ void wtprep_kernel(const float* Wl, const float* Wr, u16* Wst) {
    int idx = blockIdx.x * 256 + threadIdx.x;
    if (idx >= 32 * 128 * 8) return;
    int kb = idx >> 10, col = (idx >> 3) & 127, i = idx & 7;
    int k = kb * 8 + i;
    float v = (k < 128) ? Wl[col * 128 + k] : Wr[col * 128 + (k - 128)];
    Wst[idx] = f2bf(v);
}

// f32 x -> bf16 xb, 8 elems/thread
__global__ void cvt_kernel(const float* x, u16* xb) {
    size_t base = ((size_t)blockIdx.x * 256 + threadIdx.x) * 8;
    if (base >= (size_t)NN * 128) return;
    float4 v0 = *(const float4*)(x + base);
    float4 v1 = *(const float4*)(x + base + 4);
    uint4 w;
    w.x = (u32)f2bf(v0.x) | ((u32)f2bf(v0.y) << 16);
    w.y = (u32)f2bf(v0.z) | ((u32)f2bf(v0.w) << 16);
    w.z = (u32)f2bf(v1.x) | ((u32)f2bf(v1.y) << 16);
    w.w = (u32)f2bf(v1.z) | ((u32)f2bf(v1.w) << 16);
    *(uint4*)(xb + base) = w;
}

// One wave per node; lane owns 2 bf16 elems (4B) of the 128-wide row. f32 accumulate.
__global__ __launch_bounds__(256) void agg_kernel(const u16* feat, const int* csr,
                                                  const int* offsets, const int* cnt,
                                                  u16* aggb) {
    int node = blockIdx.x * 4 + (threadIdx.x >> 6);
    int lane = threadIdx.x & 63;
    if (node >= NN) return;
    int beg = offsets[node];
    int deg = cnt[node];
    float ax = 0.f, ay = 0.f;
    int j = 0;
    for (; j + 4 <= deg; j += 4) {
        int s0 = csr[beg + j + 0];
        int s1 = csr[beg + j + 1];
        int s2 = csr[beg + j + 2];
        int s3 = csr[beg + j + 3];
        u32 u0 = *(const u32*)(feat + (size_t)s0 * 128 + lane * 2);
        u32 u1 = *(const u32*)(feat + (size_t)s1 * 128 + lane * 2);
        u32 u2 = *(const u32*)(feat + (size_t)s2 * 128 + lane * 2);
        u32 u3 = *(const u32*)(feat + (size_t)s3 * 128 + lane * 2);
        ax += __uint_as_float(u0 << 16) + __uint_as_float(u1 << 16)
            + __uint_as_float(u2 << 16) + __uint_as_float(u3 << 16);
        ay += __uint_as_float(u0 & 0xffff0000u) + __uint_as_float(u1 & 0xffff0000u)
            + __uint_as_float(u2 & 0xffff0000u) + __uint_as_float(u3 & 0xffff0000u);
    }
    for (; j < deg; j++) {
        int s = csr[beg + j];
        u32 u = *(const u32*)(feat + (size_t)s * 128 + lane * 2);
        ax += __uint_as_float(u << 16);
        ay += __uint_as_float(u & 0xffff0000u);
    }
    float inv = (deg > 0) ? 1.0f / (float)deg : 0.0f;
    u32 packed = (u32)f2bf(ax * inv) | ((u32)f2bf(ay * inv) << 16);
    *(u32*)(aggb + (size_t)node * 128 + lane * 2) = packed;
}

// MFMA GEMM: out[n,o] = sum_k [A||B][n,k] * W[k,o] + bias[o], K=256.
__global__ __launch_bounds__(256) void lin_kernel(const u16* __restrict__ Abuf,
                                                  const u16* __restrict__ Bbuf,
                                                  const u16* __restrict__ Wst,
                                                  const float* __restrict__ bias,
                                                  float* outF, u16* outH, int relu) {
    __shared__ u16 As[128][136];   // +8 pad: rows 4 banks apart
    __shared__ u16 Ws[16384];      // [16 kb][128 col][8 k] bf16, chunk-local

    int tid = threadIdx.x;
    int lane = tid & 63;
    int wid = tid >> 6;
    int wr = wid >> 1, wc = wid & 1;
    int nb = blockIdx.x * 128;
    int l15 = lane & 15, l4 = lane >> 4;

    f32x4 acc[4][4];
#pragma unroll
    for (int i = 0; i < 4; i++)
#pragma unroll
        for (int j = 0; j < 4; j++) acc[i][j] = (f32x4){0.f, 0.f, 0.f, 0.f};

    for (int c = 0; c < 2; c++) {
        const u16* Base = c ? Bbuf : Abuf;
        __syncthreads();

#pragma unroll
        for (int it = 0; it < 8; it++) {
            int idx = it * 256 + tid;
            int row = idx >> 4, c16 = idx & 15;
            float4 v = make_float4(0.f, 0.f, 0.f, 0.f);
            if (nb + row < NN)
                v = *(const float4*)(Base + (size_t)(nb + row) * 128 + c16 * 8);
            *(float4*)&As[row][c16 * 8] = v;
        }
        const u16* wsrc = Wst + c * 16384;
#pragma unroll
        for (int it = 0; it < 8; it++) {
            int idx = it * 256 + tid;
            *(float4*)&Ws[idx * 8] = *(const float4*)(wsrc + idx * 8);
        }
        __syncthreads();

#pragma unroll
        for (int kk = 0; kk < 4; kk++) {
            frag a[4], b[4];
#pragma unroll
            for (int i = 0; i < 4; i++)
                a[i] = *(const frag*)&As[wr * 64 + i * 16 + l15][kk * 32 + l4 * 8];
#pragma unroll
            for (int j = 0; j < 4; j++)
                b[j] = *(const frag*)&Ws[((kk * 4 + l4) * 128 + wc * 64 + j * 16 + l15) * 8];
#pragma unroll
            for (int i = 0; i < 4; i++)
#pragma unroll
                for (int j = 0; j < 4; j++)
                    acc[i][j] = __builtin_amdgcn_mfma_f32_16x16x32_bf16(a[i], b[j], acc[i][j], 0, 0, 0);
        }
    }

    // epilogue: C/D layout col = lane&15, row = (lane>>4)*4 + reg
#pragma unroll
    for (int j = 0; j < 4; j++) {
        int col = wc * 64 + j * 16 + l15;
        float bv = bias[col];
#pragma unroll
        for (int i = 0; i < 4; i++) {
#pragma unroll
            for (int r = 0; r < 4; r++) {
                int node = nb + wr * 64 + i * 16 + l4 * 4 + r;
                if (node >= NN) continue;
                float v = acc[i][j][r] + bv;
                if (relu) {
                    v = fmaxf(v, 0.f);
                    outH[(size_t)node * 128 + col] = f2bf(v);
                } else {
                    outF[(size_t)node * 128 + col] = v;
                }
            }
        }
    }
}

extern "C" void kernel_launch(void* const* d_in, const int* in_sizes, int n_in,
                              void* d_out, int out_size, void* d_ws, size_t ws_size,
                              hipStream_t stream) {
    const float* x    = (const float*)d_in[0];
    const void* edges = d_in[1];
    const float* Wl1  = (const float*)d_in[2];
    const float* Wr1  = (const float*)d_in[3];
    const float* b1   = (const float*)d_in[4];
    const float* Wl2  = (const float*)d_in[5];
    const float* Wr2  = (const float*)d_in[6];
    const float* b2   = (const float*)d_in[7];
    float* out = (float*)d_out;

    char* ws = (char*)d_ws;
    int* cnt     = (int*)(ws + OFF_CNT);
    int* offsets = (int*)(ws + OFF_OFFS);
    int* cursor  = (int*)(ws + OFF_CUR);
    int* ptail   = (int*)(ws + OFF_TAIL);        // 8 ints
    int* psum    = (int*)(ws + OFF_TAIL + 32);   // 8 ints
    int* flag    = (int*)(ws + OFF_TAIL + 64);
    int* csr     = (int*)(ws + OFF_CSR);
    u16* Wst1    = (u16*)(ws + OFF_WT1);
    u16* Wst2    = (u16*)(ws + OFF_WT2);
    u16* xb      = (u16*)(ws + OFF_XB);    // becomes hb after lin1 (in-place)
    u16* aggb    = (u16*)(ws + OFF_AGGB);

    hipMemsetAsync(cnt, 0, NN * sizeof(int), stream);
    hipMemsetAsync(cursor, 0, NN * sizeof(int), stream);

    detect_kernel<<<1, 1, 0, stream>>>(edges, flag);
    count_kernel<<<(NE + 255) / 256, 256, 0, stream>>>(edges, flag, cnt);
    psum_kernel<<<NPART, 256, 0, stream>>>(cnt, psum);
    pbase_kernel<<<1, 64, 0, stream>>>(psum, ptail);
    alloc_part_kernel<<<(NN + 255) / 256, 256, 0, stream>>>(cnt, offsets, ptail);
    fill_part_kernel<<<NPART * NCHUNK, 256, 0, stream>>>(edges, flag, offsets, cursor, csr);

    wtprep_kernel<<<128, 256, 0, stream>>>(Wl1, Wr1, Wst1);
    wtprep_kernel<<<128, 256, 0, stream>>>(Wl2, Wr2, Wst2);
    cvt_kernel<<<6250, 256, 0, stream>>>(x, xb);

    int lgrid = (NN + 127) / 128;  // 782

    // layer 1: agg1 = mean-gather(xb); h = relu(lin(agg1, xb)) -> bf16 in-place into xb
    agg_kernel<<<NN / 4, 256, 0, stream>>>(xb, csr, offsets, cnt, aggb);
    lin_kernel<<<lgrid, 256, 0, stream>>>(aggb, xb, Wst1, b1, nullptr, xb, 1);

    // layer 2: agg2 = mean-gather(hb); out = lin(agg2, hb) -> f32 d_out
    agg_kernel<<<NN / 4, 256, 0, stream>>>(xb, csr, offsets, cnt, aggb);
    lin_kernel<<<lgrid, 256, 0, stream>>>(aggb, xb, Wst2, b2, out, nullptr, 0);
}

// Round 6
// 291.558 us; speedup vs baseline: 1.3982x; 1.3982x over previous
//
#include <hip/hip_runtime.h>
#include <hip/hip_bf16.h>

#define NN 100000
#define NE 1600000
#define BNODES 196          // nodes per bucket
#define NB 511              // ceil(NN/BNODES)
#define NBLKA 256           // blocks in hist/scatter
#define CHUNK 6250          // NE / NBLKA, exact

typedef unsigned short u16;
typedef unsigned int u32;
using frag  = __attribute__((ext_vector_type(8))) short;   // 8 bf16 = 4 VGPR
using f32x4 = __attribute__((ext_vector_type(4))) float;   // MFMA C/D

// ---------------- workspace layout (byte offsets), total 60,637,184 B ----------------
#define OFF_CNT   (0)                 // NN int
#define OFF_OFFS  (512u << 10)        // NN int
#define OFF_BB    (1u << 20)          // NB+2 int  (bucket bases, bb[NB]=NE)
#define OFF_H     (1310720u)          // NBLKA*512 int = 512KB (dead after A3)
#define OFF_CSR   (2u << 20)          // NE int
#define OFF_WT1   (8704u << 10)       // 32KB bf16 packed
#define OFF_WT2   ((8704u << 10) + 65536u)
#define OFF_XB    (9u << 20)          // NN*128 bf16 = 25.6MB (becomes hb in-place)
#define OFF_AGGB  (35037184u)         // NN*128 bf16 = 25.6MB
#define OFF_REC   (54237184u)         // NE u32 = 6.4MB, overlaps aggb tail (dead by agg)

// round-to-nearest-even f32 -> bf16 bits
__device__ __forceinline__ u16 f2bf(float f) {
    u32 u = __float_as_uint(f);
    u32 r = u + 0x7fffu + ((u >> 16) & 1u);
    return (u16)(r >> 16);
}

// per-block int64/int32 detection (no global flag, no extra kernel)
__device__ __forceinline__ bool edges_are_i64(const void* edges) {
    const long long* e = (const long long*)edges;
    bool ok = true;
#pragma unroll
    for (int i = 0; i < 4; i++) {
        long long v = e[i];
        if (v < 0 || v >= NN) ok = false;
    }
    return ok;
}

// A1: per-block LDS histogram over buckets (LDS atomics only)
__global__ __launch_bounds__(256) void hist_kernel(const void* edges, int* H) {
    __shared__ int h[512];
    int tid = threadIdx.x, blk = blockIdx.x;
    for (int i = tid; i < 512; i += 256) h[i] = 0;
    __syncthreads();
    bool f = edges_are_i64(edges);
    int lo = blk * CHUNK, hi = lo + CHUNK;
    if (f) {
        const long long* dst = (const long long*)edges + NE;
        for (int i = lo + tid; i < hi; i += 256) atomicAdd(&h[(int)dst[i] / BNODES], 1);
    } else {
        const int* dst = (const int*)edges + NE;
        for (int i = lo + tid; i < hi; i += 256) atomicAdd(&h[dst[i] / BNODES], 1);
    }
    __syncthreads();
    for (int i = tid; i < 512; i += 256) H[blk * 512 + i] = h[i];
}

// A2: H[blk][b] -> exclusive prefix over blk, + bucket bases bb[]; rebase H to global indices
__global__ void scan_kernel(int* H, int* bb) {
    __shared__ int sc[512];
    int b = threadIdx.x;  // 512 threads
    int s = 0;
    for (int blk = 0; blk < NBLKA; blk++) {
        int v = H[blk * 512 + b];
        H[blk * 512 + b] = s;
        s += v;
    }
    sc[b] = s;
    __syncthreads();
    for (int off = 1; off < 512; off <<= 1) {
        int v = (b >= off) ? sc[b - off] : 0;
        __syncthreads();
        sc[b] += v;
        __syncthreads();
    }
    bb[b] = sc[b] - s;          // exclusive bucket base
    if (b == 511) bb[512] = sc[511];
    __syncthreads();
    int base = bb[b];
    for (int blk = 0; blk < NBLKA; blk++) H[blk * 512 + b] += base;
}

// A3: scatter packed records (dst_local<<17 | src) into exact per-(block,bucket) regions
__global__ __launch_bounds__(256) void scatter_kernel(const void* edges, const int* H, u32* rec) {
    __shared__ int cur[512];
    int tid = threadIdx.x, blk = blockIdx.x;
    for (int i = tid; i < 512; i += 256) cur[i] = H[blk * 512 + i];
    __syncthreads();
    bool f = edges_are_i64(edges);
    int lo = blk * CHUNK, hi = lo + CHUNK;
    if (f) {
        const long long* e = (const long long*)edges;
        for (int i = lo + tid; i < hi; i += 256) {
            int d = (int)e[NE + i], s = (int)e[i];
            int b = d / BNODES;
            int p = atomicAdd(&cur[b], 1);
            rec[p] = ((u32)(d - b * BNODES) << 17) | (u32)s;
        }
    } else {
        const int* e = (const int*)edges;
        for (int i = lo + tid; i < hi; i += 256) {
            int d = e[NE + i], s = e[i];
            int b = d / BNODES;
            int p = atomicAdd(&cur[b], 1);
            rec[p] = ((u32)(d - b * BNODES) << 17) | (u32)s;
        }
    }
}

// B: per-bucket: LDS hist -> prefix -> cnt/offsets (no atomics) -> csr scatter in own window
__global__ __launch_bounds__(256) void bucket_csr_kernel(const u32* rec, const int* bb,
                                                         int* cnt, int* offsets, int* csr) {
    __shared__ int hcnt[200], hpre[200], hcur[200];
    int b = blockIdx.x, tid = threadIdx.x;
    int base = bb[b], total = bb[b + 1] - base;
    for (int i = tid; i < BNODES; i += 256) hcnt[i] = 0;
    __syncthreads();
    for (int i = tid; i < total; i += 256) atomicAdd(&hcnt[rec[base + i] >> 17], 1);
    __syncthreads();
    if (tid < 64) {  // wave 0: exclusive prefix over 196 counters (49 lanes x 4)
        int l = tid;
        int s0 = 0, s1 = 0, s2 = 0, s3 = 0;
        if (l < 49) {
            s0 = hcnt[l * 4]; s1 = hcnt[l * 4 + 1]; s2 = hcnt[l * 4 + 2]; s3 = hcnt[l * 4 + 3];
        }
        int t0 = s0, t1 = t0 + s1, t2 = t1 + s2, t3 = t2 + s3;
        int sc = t3;
#pragma unroll
        for (int off = 1; off < 64; off <<= 1) {
            int v = __shfl_up(sc, off, 64);
            if (l >= off) sc += v;
        }
        int lbase = sc - t3;
        if (l < 49) {
            hpre[l * 4] = lbase;      hpre[l * 4 + 1] = lbase + t0;
            hpre[l * 4 + 2] = lbase + t1; hpre[l * 4 + 3] = lbase + t2;
        }
    }
    __syncthreads();
    int node0 = b * BNODES;
    for (int i = tid; i < BNODES; i += 256) {
        int n = node0 + i;
        if (n < NN) { cnt[n] = hcnt[i]; offsets[n] = base + hpre[i]; }
    }
    for (int i = tid; i < BNODES; i += 256) hcur[i] = hpre[i];
    __syncthreads();
    for (int i = tid; i < total; i += 256) {
        u32 r = rec[base + i];
        int p = atomicAdd(&hcur[r >> 17], 1);
        csr[base + p] = (int)(r & 0x1FFFFu);
    }
}

// both layers' weights in one launch: blocks 0..127 -> W1, 128..255 -> W2
__global__ void wtprep_kernel(const float* Wl1, const float* Wr1,
                              const float* Wl2, const float* Wr2, u16* Wst1, u16* Wst2) {
    int gid = blockIdx.x * 256 + threadIdx.x;
    int idx = gid & (32 * 128 * 8 - 1);
    const float* Wl = (gid < 32768) ? Wl1 : Wl2;
    const float* Wr = (gid < 32768) ? Wr1 : Wr2;
    u16* Wst = (gid < 32768) ? Wst1 : Wst2;
    int kb = idx >> 10, col = (idx >> 3) & 127, i = idx & 7;
    int k = kb * 8 + i;
    float v = (k < 128) ? Wl[col * 128 + k] : Wr[col * 128 + (k - 128)];
    Wst[idx] = f2bf(v);
}

// f32 x -> bf16 xb, 8 elems/thread
__global__ void cvt_kernel(const float* x, u16* xb) {
    size_t base = ((size_t)blockIdx.x * 256 + threadIdx.x) * 8;
    if (base >= (size_t)NN * 128) return;
    float4 v0 = *(const float4*)(x + base);
    float4 v1 = *(const float4*)(x + base + 4);
    uint4 w;
    w.x = (u32)f2bf(v0.x) | ((u32)f2bf(v0.y) << 16);
    w.y = (u32)f2bf(v0.z) | ((u32)f2bf(v0.w) << 16);
    w.z = (u32)f2bf(v1.x) | ((u32)f2bf(v1.y) << 16);
    w.w = (u32)f2bf(v1.z) | ((u32)f2bf(v1.w) << 16);
    *(uint4*)(xb + base) = w;
}

// One wave per node; lane owns 2 bf16 cols (4B) of the 128-wide row; f32 accumulate.
__global__ __launch_bounds__(256) void agg_kernel(const u16* feat, const int* csr,
                                                  const int* offsets, const int* cnt,
                                                  u16* aggb) {
    int node = blockIdx.x * 4 + (threadIdx.x >> 6);
    int lane = threadIdx.x & 63;
    if (node >= NN) return;
    int beg = offsets[node];
    int deg = cnt[node];
    float ax = 0.f, ay = 0.f;
    int j = 0;
    for (; j + 4 <= deg; j += 4) {
        int s0 = csr[beg + j + 0];
        int s1 = csr[beg + j + 1];
        int s2 = csr[beg + j + 2];
        int s3 = csr[beg + j + 3];
        u32 u0 = *(const u32*)(feat + (size_t)s0 * 128 + lane * 2);
        u32 u1 = *(const u32*)(feat + (size_t)s1 * 128 + lane * 2);
        u32 u2 = *(const u32*)(feat + (size_t)s2 * 128 + lane * 2);
        u32 u3 = *(const u32*)(feat + (size_t)s3 * 128 + lane * 2);
        ax += __uint_as_float(u0 << 16) + __uint_as_float(u1 << 16)
            + __uint_as_float(u2 << 16) + __uint_as_float(u3 << 16);
        ay += __uint_as_float(u0 & 0xffff0000u) + __uint_as_float(u1 & 0xffff0000u)
            + __uint_as_float(u2 & 0xffff0000u) + __uint_as_float(u3 & 0xffff0000u);
    }
    for (; j < deg; j++) {
        int s = csr[beg + j];
        u32 u = *(const u32*)(feat + (size_t)s * 128 + lane * 2);
        ax += __uint_as_float(u << 16);
        ay += __uint_as_float(u & 0xffff0000u);
    }
    float inv = (deg > 0) ? 1.0f / (float)deg : 0.0f;
    u32 packed = (u32)f2bf(ax * inv) | ((u32)f2bf(ay * inv) << 16);
    *(u32*)(aggb + (size_t)node * 128 + lane * 2) = packed;
}

// MFMA GEMM: out[n,o] = sum_k [A||B][n,k] * W[k,o] + bias[o], K=256.
__global__ __launch_bounds__(256) void lin_kernel(const u16* __restrict__ Abuf,
                                                  const u16* __restrict__ Bbuf,
                                                  const u16* __restrict__ Wst,
                                                  const float* __restrict__ bias,
                                                  float* outF, u16* outH, int relu) {
    __shared__ u16 As[128][136];   // +8 pad: rows 4 banks apart
    __shared__ u16 Ws[16384];      // [16 kb][128 col][8 k] bf16, chunk-local

    int tid = threadIdx.x;
    int lane = tid & 63;
    int wid = tid >> 6;
    int wr = wid >> 1, wc = wid & 1;
    int nb = blockIdx.x * 128;
    int l15 = lane & 15, l4 = lane >> 4;

    f32x4 acc[4][4];
#pragma unroll
    for (int i = 0; i < 4; i++)
#pragma unroll
        for (int j = 0; j < 4; j++) acc[i][j] = (f32x4){0.f, 0.f, 0.f, 0.f};

    for (int c = 0; c < 2; c++) {
        const u16* Base = c ? Bbuf : Abuf;
        __syncthreads();

#pragma unroll
        for (int it = 0; it < 8; it++) {
            int idx = it * 256 + tid;
            int row = idx >> 4, c16 = idx & 15;
            float4 v = make_float4(0.f, 0.f, 0.f, 0.f);
            if (nb + row < NN)
                v = *(const float4*)(Base + (size_t)(nb + row) * 128 + c16 * 8);
            *(float4*)&As[row][c16 * 8] = v;
        }
        const u16* wsrc = Wst + c * 16384;
#pragma unroll
        for (int it = 0; it < 8; it++) {
            int idx = it * 256 + tid;
            *(float4*)&Ws[idx * 8] = *(const float4*)(wsrc + idx * 8);
        }
        __syncthreads();

#pragma unroll
        for (int kk = 0; kk < 4; kk++) {
            frag a[4], bfr[4];
#pragma unroll
            for (int i = 0; i < 4; i++)
                a[i] = *(const frag*)&As[wr * 64 + i * 16 + l15][kk * 32 + l4 * 8];
#pragma unroll
            for (int j = 0; j < 4; j++)
                bfr[j] = *(const frag*)&Ws[((kk * 4 + l4) * 128 + wc * 64 + j * 16 + l15) * 8];
#pragma unroll
            for (int i = 0; i < 4; i++)
#pragma unroll
                for (int j = 0; j < 4; j++)
                    acc[i][j] = __builtin_amdgcn_mfma_f32_16x16x32_bf16(a[i], bfr[j], acc[i][j], 0, 0, 0);
        }
    }

    // epilogue: C/D layout col = lane&15, row = (lane>>4)*4 + reg
#pragma unroll
    for (int j = 0; j < 4; j++) {
        int col = wc * 64 + j * 16 + l15;
        float bv = bias[col];
#pragma unroll
        for (int i = 0; i < 4; i++) {
#pragma unroll
            for (int r = 0; r < 4; r++) {
                int node = nb + wr * 64 + i * 16 + l4 * 4 + r;
                if (node >= NN) continue;
                float v = acc[i][j][r] + bv;
                if (relu) {
                    v = fmaxf(v, 0.f);
                    outH[(size_t)node * 128 + col] = f2bf(v);
                } else {
                    outF[(size_t)node * 128 + col] = v;
                }
            }
        }
    }
}

extern "C" void kernel_launch(void* const* d_in, const int* in_sizes, int n_in,
                              void* d_out, int out_size, void* d_ws, size_t ws_size,
                              hipStream_t stream) {
    const float* x    = (const float*)d_in[0];
    const void* edges = d_in[1];
    const float* Wl1  = (const float*)d_in[2];
    const float* Wr1  = (const float*)d_in[3];
    const float* b1   = (const float*)d_in[4];
    const float* Wl2  = (const float*)d_in[5];
    const float* Wr2  = (const float*)d_in[6];
    const float* b2   = (const float*)d_in[7];
    float* out = (float*)d_out;

    char* ws = (char*)d_ws;
    int* cnt     = (int*)(ws + OFF_CNT);
    int* offsets = (int*)(ws + OFF_OFFS);
    int* bb      = (int*)(ws + OFF_BB);
    int* H       = (int*)(ws + OFF_H);
    int* csr     = (int*)(ws + OFF_CSR);
    u16* Wst1    = (u16*)(ws + OFF_WT1);
    u16* Wst2    = (u16*)(ws + OFF_WT2);
    u16* xb      = (u16*)(ws + OFF_XB);    // becomes hb after lin1 (in-place)
    u16* aggb    = (u16*)(ws + OFF_AGGB);
    u32* rec     = (u32*)(ws + OFF_REC);   // overlaps aggb tail; dead before agg1

    // CSR build: zero global atomics
    hist_kernel<<<NBLKA, 256, 0, stream>>>(edges, H);
    scan_kernel<<<1, 512, 0, stream>>>(H, bb);
    scatter_kernel<<<NBLKA, 256, 0, stream>>>(edges, H, rec);
    bucket_csr_kernel<<<NB, 256, 0, stream>>>(rec, bb, cnt, offsets, csr);

    wtprep_kernel<<<256, 256, 0, stream>>>(Wl1, Wr1, Wl2, Wr2, Wst1, Wst2);
    cvt_kernel<<<6250, 256, 0, stream>>>(x, xb);

    int lgrid = (NN + 127) / 128;  // 782

    // layer 1: agg1 = mean-gather(xb); h = relu(lin(agg1, xb)) -> bf16 in-place into xb
    agg_kernel<<<NN / 4, 256, 0, stream>>>(xb, csr, offsets, cnt, aggb);
    lin_kernel<<<lgrid, 256, 0, stream>>>(aggb, xb, Wst1, b1, nullptr, xb, 1);

    // layer 2: agg2 = mean-gather(hb); out = lin(agg2, hb) -> f32 d_out
    agg_kernel<<<NN / 4, 256, 0, stream>>>(xb, csr, offsets, cnt, aggb);
    lin_kernel<<<lgrid, 256, 0, stream>>>(aggb, xb, Wst2, b2, out, nullptr, 0);
}